// Round 3
// baseline (1284.512 us; speedup 1.0000x reference)
//
#include <hip/hip_runtime.h>
#include <hip/hip_bf16.h>

#define N_NODES 262144
#define E_EDGES 4194304
#define EPAD    4194310   // E + 6
#define LAT_N   524288    // 32768 * 16  (f32 elements, output 0)
#define SRC_OFF 524288
#define DST_OFF (524288 + 4194310)
#define W_OFF   (524288 + 2 * 4194310)

// ---------------------------------------------------------------------------
// Output edges + w (f32 out): closed form.
// src/dst pads: (131071,0),(0,131071),(65535,0),(0,65535),(32767,0),(0,32767)
// w[e<E] = (src<32768 && dst<32768); w pads = 0,0,0,0,1,1
// ---------------------------------------------------------------------------
__global__ void edges_out_kernel(const int* __restrict__ ei, float* __restrict__ out) {
    int e = blockIdx.x * 256 + threadIdx.x;
    if (e >= EPAD) return;
    int s, d; float w;
    if (e < E_EDGES) {
        s = ei[e];
        d = ei[E_EDGES + e];
        w = (s < 32768 && d < 32768) ? 1.0f : 0.0f;
    } else {
        int k = e - E_EDGES;      // 0..5
        int stage = k >> 1;       // 0,1,2
        int m = 131072 >> stage;  // 131072, 65536, 32768
        if ((k & 1) == 0) { s = m - 1; d = 0; } else { s = 0; d = m - 1; }
        w = (stage == 2) ? 1.0f : 0.0f;
    }
    out[SRC_OFF + e] = (float)s;
    out[DST_OFF + e] = (float)d;
    out[W_OFF + e]   = w;
}

// ---------------------------------------------------------------------------
// Degree accumulation (deg[dst] += 1 for active edges; pads for stages 2/3).
// ---------------------------------------------------------------------------
__global__ void deg_kernel(const int* __restrict__ ei, float* __restrict__ deg,
                           int n, int pads) {
    int e = blockIdx.x * 256 + threadIdx.x;
    if (e >= E_EDGES + 2) return;
    int d;
    if (e < E_EDGES) {
        int s = ei[e];
        d = ei[E_EDGES + e];
        if (s >= n || d >= n) return;
    } else {
        if (!pads) return;
        d = (e == E_EDGES) ? 0 : (n - 1);
    }
    atomicAdd(&deg[d], 1.0f);
}

// ---------------------------------------------------------------------------
// Fused: dinv = rsqrt(deg+1) (overwrites deg in place), h = x @ W (bf16 out),
//        agg = dinv^2 * h + b   (self-loop term + bias init)
// FIN = 32 always. One thread per (node, out-feature).
// ---------------------------------------------------------------------------
template <int FOUT>
__global__ void xform_kernel(const float* __restrict__ xin,
                             const float* __restrict__ W,
                             const float* __restrict__ b,
                             float* deg_dinv,
                             __hip_bfloat16* __restrict__ h,
                             float* __restrict__ agg,
                             int n) {
    constexpr int FIN = 32;
    constexpr int NPB = 256 / FOUT;  // nodes per block
    __shared__ float sW[FIN * FOUT];
    __shared__ float sb[FOUT];
    __shared__ float sx[NPB * FIN];

    int tid = threadIdx.x;
    for (int i = tid; i < FIN * FOUT; i += 256) sW[i] = W[i];
    if (tid < FOUT) sb[tid] = b[tid];

    int node0 = blockIdx.x * NPB;
    for (int i = tid; i < NPB * FIN; i += 256) sx[i] = xin[node0 * FIN + i];

    int nl = tid / FOUT;
    int j  = tid % FOUT;
    int node = node0 + nl;
    float dg = deg_dinv[node];          // read BEFORE overwrite
    __syncthreads();
    float di = rsqrtf(dg + 1.0f);
    if (j == 0) deg_dinv[node] = di;    // in-place: deg -> dinv

    float acc = 0.0f;
#pragma unroll
    for (int k = 0; k < FIN; ++k) acc += sx[nl * FIN + k] * sW[k * FOUT + j];

    h[node * FOUT + j]   = __float2bfloat16(acc);
    agg[node * FOUT + j] = di * di * acc + sb[j];
}

// ---------------------------------------------------------------------------
// Edge scatter: agg[dst] += dinv[src]*dinv[dst]*h[src]. FOUT threads per edge.
// ---------------------------------------------------------------------------
template <int FOUT>
__global__ void scatter_kernel(const int* __restrict__ ei,
                               const float* __restrict__ dinv,
                               const __hip_bfloat16* __restrict__ h,
                               float* agg, int n, int pads) {
    unsigned int idx = blockIdx.x * 256u + threadIdx.x;
    const unsigned int total = (unsigned int)(E_EDGES + 2) * FOUT;
    if (idx >= total) return;
    int e = (int)(idx / FOUT);
    int f = (int)(idx % FOUT);
    int s, d;
    if (e < E_EDGES) {
        s = ei[e];
        d = ei[E_EDGES + e];
        if (s >= n || d >= n) return;
    } else {
        if (!pads) return;
        if (e == E_EDGES) { s = n - 1; d = 0; } else { s = 0; d = n - 1; }
    }
    float nm = dinv[s] * dinv[d];
    atomicAdd(&agg[d * FOUT + f], nm * __bfloat162float(h[s * FOUT + f]));
}

// ---------------------------------------------------------------------------
// relu + pairwise max pool (relu∘max == max∘relu since relu is monotone)
// ---------------------------------------------------------------------------
template <int F>
__global__ void pool_kernel(const float* __restrict__ agg, float* __restrict__ out, int m) {
    unsigned int idx = blockIdx.x * 256u + threadIdx.x;
    if (idx >= (unsigned int)m * F) return;
    int i = idx / F, f = idx % F;
    float a = agg[(2 * i) * F + f];
    float c = agg[(2 * i + 1) * F + f];
    out[idx] = fmaxf(fmaxf(a, c), 0.0f);
}

// final pool -> f32 output (m = 32768, F = 16)
__global__ void pool_out_kernel(const float* __restrict__ agg, float* __restrict__ out) {
    unsigned int idx = blockIdx.x * 256u + threadIdx.x;
    if (idx >= 32768u * 16u) return;
    unsigned int i = idx >> 4, f = idx & 15;
    float a = agg[32 * i + f];
    float c = agg[32 * i + 16 + f];
    out[idx] = fmaxf(fmaxf(a, c), 0.0f);
}

// ---------------------------------------------------------------------------
// Workspace layout (49 MB peak):
//   byte 0        .. 32MB : AGG  (f32; stage1 full, stage2 first 16MB, stage3 first 4MB)
//   byte 32MB     .. 48MB : H1 bf16 (16MB)  -> then POOL1 f32 (16MB) -> then POOL2 f32 (8MB)
//   byte 16MB     .. 24MB : H2 bf16 (8MB, over dead AGG1 tail) -> then H3 bf16 (2MB)
//   byte 48MB     .. 49MB : DEG/DINV f32 (1MB; stage prefix)
// ---------------------------------------------------------------------------
extern "C" void kernel_launch(void* const* d_in, const int* in_sizes, int n_in,
                              void* d_out, int out_size, void* d_ws, size_t ws_size,
                              hipStream_t stream) {
    const float* x  = (const float*)d_in[0];
    const int*   ei = (const int*)d_in[1];
    const float* W1 = (const float*)d_in[2];
    const float* b1 = (const float*)d_in[3];
    const float* W2 = (const float*)d_in[4];
    const float* b2 = (const float*)d_in[5];
    const float* W3 = (const float*)d_in[6];
    const float* b3 = (const float*)d_in[7];
    float* out = (float*)d_out;

    char* ws = (char*)d_ws;
    float*          agg   = (float*)ws;                            // @0
    __hip_bfloat16* h1    = (__hip_bfloat16*)(ws + (32u << 20));   // @32MB
    float*          pool1 = (float*)(ws + (32u << 20));            // @32MB (over dead h1)
    __hip_bfloat16* h23   = (__hip_bfloat16*)(ws + (16u << 20));   // @16MB (over dead agg1 tail)
    float*          pool2 = (float*)(ws + (32u << 20));            // @32MB (over dead pool1)
    float*          deg   = (float*)(ws + (48u << 20));            // @48MB

    // edge/w outputs (closed form)
    edges_out_kernel<<<(EPAD + 255) / 256, 256, 0, stream>>>(ei, out);

    const int degBlocks = (E_EDGES + 2 + 255) / 256;

    // ---- stage 1: n = 262144, 32 -> 32, no pad edges ----
    hipMemsetAsync(deg, 0, 262144 * sizeof(float), stream);
    deg_kernel<<<degBlocks, 256, 0, stream>>>(ei, deg, 262144, 0);
    xform_kernel<32><<<262144 / 8, 256, 0, stream>>>(x, W1, b1, deg, h1, agg, 262144);
    scatter_kernel<32><<<(int)(((unsigned)(E_EDGES + 2) * 32 + 255) / 256), 256, 0, stream>>>(
        ei, deg, h1, agg, 262144, 0);
    pool_kernel<32><<<(131072 * 32 + 255) / 256, 256, 0, stream>>>(agg, pool1, 131072);

    // ---- stage 2: n = 131072, 32 -> 32, pads active ----
    hipMemsetAsync(deg, 0, 131072 * sizeof(float), stream);
    deg_kernel<<<degBlocks, 256, 0, stream>>>(ei, deg, 131072, 1);
    xform_kernel<32><<<131072 / 8, 256, 0, stream>>>(pool1, W2, b2, deg, h23, agg, 131072);
    scatter_kernel<32><<<(int)(((unsigned)(E_EDGES + 2) * 32 + 255) / 256), 256, 0, stream>>>(
        ei, deg, h23, agg, 131072, 1);
    pool_kernel<32><<<(65536 * 32 + 255) / 256, 256, 0, stream>>>(agg, pool2, 65536);

    // ---- stage 3: n = 65536, 32 -> 16, pads active ----
    hipMemsetAsync(deg, 0, 65536 * sizeof(float), stream);
    deg_kernel<<<degBlocks, 256, 0, stream>>>(ei, deg, 65536, 1);
    xform_kernel<16><<<65536 / 16, 256, 0, stream>>>(pool2, W3, b3, deg, h23, agg, 65536);
    scatter_kernel<16><<<(int)(((unsigned)(E_EDGES + 2) * 16 + 255) / 256), 256, 0, stream>>>(
        ei, deg, h23, agg, 65536, 1);
    pool_out_kernel<<<(32768 * 16 + 255) / 256, 256, 0, stream>>>(agg, out);
}